// Round 6
// baseline (363.249 us; speedup 1.0000x reference)
//
#include <hip/hip_runtime.h>

// DetectionLoss: B=16, A=65536, T=32, C=21.
// R6: rcp-based IoU (no IEEE div), phase-2 argmax from XOR-swizzled LDS IoU
// matrix (no recompute), packed anchor histogram, 8 graph nodes total:
// memset, main, force+select0, compact, hist1, refine2(+inline select1),
// selectF (exact top-rem over boundary-bin list), finalize.

#define AN 65536
#define BN 16
#define TN 32
#define CN 21
#define NBA 2048   // anchor/cell L1 bins = focal bits >> 20

struct Acc   { double pos_sum; double bbox_sum; unsigned np; unsigned nn; };
struct Chain { double sumAbove; double topk; unsigned active; unsigned k; unsigned ve;
               unsigned b1; unsigned rem; };
struct BlockAcc { float pos_sum; float bbox_sum; unsigned np; unsigned nn; };

// ---------- shared math: bit-identical across kernels (_rn-pinned, shared fns) ----------
__device__ __forceinline__ float box_area(float4 B) {
    return __fmul_rn(__fsub_rn(B.z, B.x), __fsub_rn(B.w, B.y));
}
__device__ __forceinline__ float iou_rcp(float4 A, float aa, float4 T, float ta) {
    float x1 = fmaxf(A.x, T.x), y1 = fmaxf(A.y, T.y);
    float x2 = fminf(A.z, T.z), y2 = fminf(A.w, T.w);
    float inter = __fmul_rn(fmaxf(__fsub_rn(x2, x1), 0.f), fmaxf(__fsub_rn(y2, y1), 0.f));
    float den = __fadd_rn(__fsub_rn(__fadd_rn(aa, ta), inter), 1e-6f);
    return __fmul_rn(inter, __builtin_amdgcn_rcpf(den));
}
__device__ __forceinline__ float row_prep(const float* __restrict__ row, float* __restrict__ c) {
#pragma unroll
    for (int j = 0; j < CN; ++j) c[j] = row[j];
    float m1[10];
#pragma unroll
    for (int j = 0; j < 10; ++j) m1[j] = fmaxf(c[j], c[j + 10]);
    float m2[5];
#pragma unroll
    for (int j = 0; j < 5; ++j) m2[j] = fmaxf(m1[j], m1[j + 5]);
    float ma = fmaxf(m2[0], m2[1]), mb = fmaxf(m2[2], m2[3]);
    float m = fmaxf(fmaxf(ma, mb), fmaxf(m2[4], c[20]));
#pragma unroll
    for (int j = 0; j < CN; ++j) c[j] = __expf(__fsub_rn(c[j], m));
    float s1[10];
#pragma unroll
    for (int j = 0; j < 10; ++j) s1[j] = __fadd_rn(c[j], c[j + 10]);
    float s2[5];
#pragma unroll
    for (int j = 0; j < 5; ++j) s2[j] = __fadd_rn(s1[j], s1[j + 5]);
    float sa = __fadd_rn(s2[0], s2[1]), sb = __fadd_rn(s2[2], s2[3]);
    float s = __fadd_rn(__fadd_rn(sa, sb), __fadd_rn(s2[4], c[20]));
    return __builtin_amdgcn_rcpf(s);
}
__device__ __forceinline__ float cell_focal(float cexp, float inv, bool cellpos) {
    float p = __fmul_rn(cexp, inv);
    float pt = cellpos ? p : __fsub_rn(1.0f, p);
    float af = cellpos ? 0.25f : 0.75f;
    float om = __fsub_rn(1.0f, pt);
    float lg = __logf(fmaxf(pt, 1e-6f));
    return __fmul_rn(__fmul_rn(__fmul_rn(-af, om), om), lg);
}
__device__ __forceinline__ unsigned focal_bits(float fo) {
    unsigned bits = __float_as_uint(fo);
    if (bits == 0x80000000u) bits = 0u;   // canonicalize -0.0
    return bits;
}
__device__ __forceinline__ float bbox_per(float4 b1, float4 b2) {
    float x1 = fmaxf(b1.x, b2.x), y1 = fmaxf(b1.y, b2.y);
    float x2 = fminf(b1.z, b2.z), y2 = fminf(b1.w, b2.w);
    float inter = fmaxf(x2 - x1, 0.f) * fmaxf(y2 - y1, 0.f);
    float a1 = (b1.z - b1.x) * (b1.w - b1.y);
    float a2 = (b2.z - b2.x) * (b2.w - b2.y);
    float un = a1 + a2 - inter;
    float iou = inter / (un + 1e-6f);
    float ex1 = fminf(b1.x, b2.x), ey1 = fminf(b1.y, b2.y);
    float ex2 = fmaxf(b1.z, b2.z), ey2 = fmaxf(b1.w, b2.w);
    float enc = (ex2 - ex1) * (ey2 - ey1);
    float giou = iou - (enc - un) / (enc + 1e-6f);
    float gl = 1.0f - giou;
    float l1 = 0.f, d, ad;
    d = b1.x - b2.x; ad = fabsf(d); l1 += (ad < 1.f) ? (0.5f * d * d) : (ad - 0.5f);
    d = b1.y - b2.y; ad = fabsf(d); l1 += (ad < 1.f) ? (0.5f * d * d) : (ad - 0.5f);
    d = b1.z - b2.z; ad = fabsf(d); l1 += (ad < 1.f) ? (0.5f * d * d) : (ad - 0.5f);
    d = b1.w - b2.w; ad = fabsf(d); l1 += (ad < 1.f) ? (0.5f * d * d) : (ad - 0.5f);
    return gl + 0.5f * (l1 * 0.25f);
}

// ---------- fused main: match + force-argmax + focal + anchor hist ----------
__global__ __launch_bounds__(256) void main_kernel(
    const float* __restrict__ conf, const float4* __restrict__ bboxp,
    const float4* __restrict__ anchors, const float4* __restrict__ tboxes,
    const int* __restrict__ tlabels,
    unsigned long long* __restrict__ gbest,
    unsigned* __restrict__ ahist, unsigned* __restrict__ maxb,
    BlockAcc* __restrict__ blockAcc)
{
    __shared__ float iouS[TN * 256];       // 32 KB, swizzled [t*256 + (a^t)]
    __shared__ unsigned ahp[NBA / 2];      // 4 KB packed (2 bins/u32)
    __shared__ float4 tbS[TN];
    __shared__ int tlS[TN];
    __shared__ float taS[TN];
    __shared__ float pbV[TN][8];
    __shared__ int   pbA[TN][8];
    __shared__ float rF[2][4];
    __shared__ unsigned rI[2][4];
    int b = blockIdx.y, tid = threadIdx.x;
    int a = blockIdx.x * 256 + tid;
    for (int i = tid; i < NBA / 2; i += 256) ahp[i] = 0u;
    if (tid < TN) {
        float4 T = tboxes[b * TN + tid];
        tbS[tid] = T; tlS[tid] = tlabels[b * TN + tid]; taS[tid] = box_area(T);
    }
    float4 ab = anchors[a];
    float aa = box_area(ab);
    __syncthreads();

    // phase 1: per-anchor max IoU over targets; stash IoUs in LDS
    float best = -1.0f; int bt = 0;
#pragma unroll
    for (int t = 0; t < TN; ++t) {
        float iou = iou_rcp(ab, aa, tbS[t], taS[t]);
        iouS[t * 256 + (tid ^ t)] = iou;
        if (iou > best) { best = iou; bt = t; }   // strict >: first-occurrence argmax
    }
    __syncthreads();

    // phase 2: per-target best anchor within block, from LDS matrix
    {
        int t = tid & 31, pp = tid >> 5;
        const float* col = &iouS[t * 256];
        float bv = -1.f; int ba = 0;
#pragma unroll
        for (int i2 = 0; i2 < 32; ++i2) {
            int r = pp * 32 + i2;
            float v = col[r ^ t];
            if (v > bv) { bv = v; ba = r; }
        }
        pbV[t][pp] = bv; pbA[t][pp] = ba;
    }
    __syncthreads();
    if (tid < TN) {
        float bv = -1.f; int ba = 0;
#pragma unroll
        for (int pp = 0; pp < 8; ++pp) {
            float v = pbV[tid][pp];
            if (v > bv) { bv = v; ba = pbA[tid][pp]; }
        }
        unsigned ga = blockIdx.x * 256 + (unsigned)ba;
        unsigned long long key =
            (((unsigned long long)__float_as_uint(bv)) << 32) | (unsigned long long)(unsigned)(~ga);
        atomicMax(&gbest[b * TN + tid], key);   // tie -> smaller anchor idx
    }

    // phase 3: focal (threshold classification; forced anchors fixed later)
    size_t idx = (size_t)b * AN + a;
    bool posA = best >= 0.5f;
    bool negA = best < 0.4f;
    float fs = 0.f, bper = 0.f;
    unsigned mbenc = 0u;
    if (posA || negA) {
        int label = posA ? tlS[bt] : -1;
        float c[CN];
        float inv = row_prep(conf + idx * CN, c);
        unsigned mb = 0u;
#pragma unroll
        for (int j = 0; j < CN; ++j) {
            float fo = cell_focal(c[j], inv, j == label);
            fs += fo;
            mb = max(mb, focal_bits(fo));
        }
        if (negA) {
            mbenc = (mb << 1) | 1u;
            unsigned bin = mb >> 20;
            atomicAdd(&ahp[bin >> 1], 1u << ((bin & 1) << 4));
        } else {
            bper = bbox_per(bboxp[idx], tbS[bt]);
        }
    }
    maxb[idx] = mbenc;

    // block reduce {pos_sum, bbox_sum, np, nn} -> plain store
    float vpos = posA ? fs : 0.f, vb = bper;
    unsigned inp = posA ? 1u : 0u, inn = negA ? 1u : 0u;
#pragma unroll
    for (int off = 32; off; off >>= 1) {
        vpos += __shfl_down(vpos, off, 64);
        vb   += __shfl_down(vb,   off, 64);
        inp  += __shfl_down(inp,  off, 64);
        inn  += __shfl_down(inn,  off, 64);
    }
    int wv = tid >> 6, ln = tid & 63;
    if (ln == 0) { rF[0][wv] = vpos; rF[1][wv] = vb; rI[0][wv] = inp; rI[1][wv] = inn; }
    __syncthreads();
    if (tid == 0) {
        BlockAcc ba2;
        ba2.pos_sum = rF[0][0] + rF[0][1] + rF[0][2] + rF[0][3];
        ba2.bbox_sum = rF[1][0] + rF[1][1] + rF[1][2] + rF[1][3];
        ba2.np = rI[0][0] + rI[0][1] + rI[0][2] + rI[0][3];
        ba2.nn = rI[1][0] + rI[1][1] + rI[1][2] + rI[1][3];
        blockAcc[b * 256 + blockIdx.x] = ba2;
    }
    for (int i = tid; i < NBA / 2; i += 256) {
        unsigned v = ahp[i];
        if (v) {
            if (v & 0xFFFFu) atomicAdd(&ahist[b * NBA + 2 * i], v & 0xFFFFu);
            if (v >> 16)     atomicAdd(&ahist[b * NBA + 2 * i + 1], v >> 16);
        }
    }
}

// ---------- force-match fix + totals + threshold (merged, 1 block/image) ----------
__global__ __launch_bounds__(256) void force_sel0_kernel(
    const float* __restrict__ conf, const float4* __restrict__ bboxp,
    const float4* __restrict__ anchors, const float4* __restrict__ tboxes,
    const int* __restrict__ tlabels,
    const unsigned long long* __restrict__ gbest,
    const BlockAcc* __restrict__ blockAcc,
    unsigned* __restrict__ ahist, unsigned* __restrict__ maxb,
    Acc* __restrict__ acc, Chain* __restrict__ chains)
{
    __shared__ unsigned gaS[TN];
    __shared__ float4 tbS[TN];
    __shared__ int tlS[TN];
    __shared__ float dps[TN], dbb[TN];
    __shared__ int dnp[TN], dnn[TN];
    int b = blockIdx.x, tid = threadIdx.x;
    if (tid < TN) {
        gaS[tid] = ~(unsigned)(gbest[b * TN + tid] & 0xFFFFFFFFull);
        float4 T = tboxes[b * TN + tid];
        tbS[tid] = T; tlS[tid] = tlabels[b * TN + tid];
        dps[tid] = 0.f; dbb[tid] = 0.f; dnp[tid] = 0; dnn[tid] = 0;
    }
    __syncthreads();
    if (tid < TN) {
        bool doit = true;
        unsigned ga = gaS[tid];
        for (int u = 0; u < tid; ++u) if (gaS[u] == ga) doit = false;   // dedupe
        if (doit) {
            size_t idx = (size_t)b * AN + ga;
            float4 ab = anchors[ga];
            float aa = box_area(ab);
            float best = -1.f; int bt = 0;
#pragma unroll
            for (int t = 0; t < TN; ++t) {
                float4 T = tbS[t];
                float iou = iou_rcp(ab, aa, T, box_area(T));   // bit-identical to main
                if (iou > best) { best = iou; bt = t; }
            }
            if (best < 0.5f) {   // not already pos via threshold
                int label = tlS[bt];
                float c[CN];
                float inv = row_prep(conf + idx * CN, c);
                float fsv = 0.f;
#pragma unroll
                for (int j = 0; j < CN; ++j) fsv += cell_focal(c[j], inv, j == label);
                dps[tid] = fsv;
                dbb[tid] = bbox_per(bboxp[idx], tbS[bt]);
                dnp[tid] = 1;
                if (best < 0.4f) {   // was counted neg: undo
                    unsigned mbv = maxb[idx];
                    atomicSub(&ahist[b * NBA + (mbv >> 21)], 1u);
                    maxb[idx] = 0u;
                    dnn[tid] = -1;
                }
            }
        }
    }
    __threadfence();
    __syncthreads();

    // totals
    BlockAcc ba = blockAcc[b * 256 + tid];
    double ps = (double)ba.pos_sum, bs = (double)ba.bbox_sum;
    unsigned np = ba.np, nn = ba.nn;
#pragma unroll
    for (int off = 32; off; off >>= 1) {
        ps += __shfl_down(ps, off, 64);
        bs += __shfl_down(bs, off, 64);
        np += __shfl_down(np, off, 64);
        nn += __shfl_down(nn, off, 64);
    }
    __shared__ double sps[4], sbs[4];
    __shared__ unsigned snp[4], snn[4];
    __shared__ unsigned s_nn, s_np;
    int wv = tid >> 6, ln = tid & 63;
    if (ln == 0) { sps[wv] = ps; sbs[wv] = bs; snp[wv] = np; snn[wv] = nn; }
    __syncthreads();
    if (tid == 0) {
        double dp = 0, db = 0; int cp = 0, cn = 0;
        for (int i = 0; i < TN; ++i) { dp += dps[i]; db += dbb[i]; cp += dnp[i]; cn += dnn[i]; }
        Acc A;
        A.pos_sum = sps[0] + sps[1] + sps[2] + sps[3] + dp;
        A.bbox_sum = sbs[0] + sbs[1] + sbs[2] + sbs[3] + db;
        A.np = (unsigned)((int)(snp[0] + snp[1] + snp[2] + snp[3]) + cp);
        A.nn = (unsigned)((int)(snn[0] + snn[1] + snn[2] + snn[3]) + cn);
        acc[b] = A;
        s_np = A.np; s_nn = A.nn;
    }
    __syncthreads();
    unsigned nnT = s_nn, npT = s_np;
    if (nnT == 0) return;   // chain inactive; finalize uses pos-only branch
    unsigned k = min(3u * npT, nnT);

    // anchor-max threshold scan over 2048 bins
    const unsigned* h = ahist + b * NBA;
    unsigned lc[8], ccnt = 0;
#pragma unroll
    for (int i = 0; i < 8; ++i) { lc[i] = h[tid * 8 + i]; ccnt += lc[i]; }
    __shared__ unsigned scnt[256];
    scnt[tid] = ccnt;
    __syncthreads();
    for (int off = 1; off < 256; off <<= 1) {
        unsigned vc = (tid + off < 256) ? scnt[tid + off] : 0u;
        __syncthreads();
        scnt[tid] += vc;
        __syncthreads();
    }
    unsigned aboveCnt = (tid < 255) ? scnt[tid + 1] : 0u;
    if (aboveCnt < k && aboveCnt + ccnt >= k) {
        unsigned acc2 = aboveCnt;
        for (int i = 7; i >= 0; --i) {
            if (acc2 + lc[i] >= k) {
                unsigned bin = (unsigned)(tid * 8 + i);
                chains[b].active = 1;
                chains[b].k = k;
                chains[b].ve = (bin << 21) | 1u;   // encoded threshold in maxb space
                break;
            }
            acc2 += lc[i];
        }
    }
}

// ---------- compact: candidate anchors (coalesced maxb read, ballot) ----------
__global__ __launch_bounds__(256) void compact_kernel(
    const unsigned* __restrict__ maxb, const Chain* __restrict__ chains,
    int* __restrict__ cand, unsigned* __restrict__ cand_cnt)
{
    int b = blockIdx.y, tid = threadIdx.x;
    if (!chains[b].active) return;
    unsigned ve = chains[b].ve;
    int a = blockIdx.x * 256 + tid;
    size_t idx = (size_t)b * AN + a;
    bool q = (maxb[idx] >= ve);
    unsigned long long msk = __ballot(q);
    int wv = tid >> 6, ln = tid & 63;
    __shared__ unsigned wbase[4];
    __shared__ unsigned nonzero;
    if (tid == 0) nonzero = 0;
    __syncthreads();
    if (ln == 0) { wbase[wv] = (unsigned)__popcll(msk); if (msk) atomicOr(&nonzero, 1u); }
    __syncthreads();
    if (!nonzero) return;
    if (tid == 0) {
        unsigned tot = wbase[0] + wbase[1] + wbase[2] + wbase[3];
        unsigned base = atomicAdd(&cand_cnt[b], tot);
        unsigned run = base;
        for (int w = 0; w < 4; ++w) { unsigned t2 = wbase[w]; wbase[w] = run; run += t2; }
    }
    __syncthreads();
    if (q) {
        unsigned pre = (unsigned)__popcll(msk & ((ln == 63) ? ~0ULL >> 1 : ((1ULL << (ln + 1)) - 1ULL) >> 1));
        cand[(size_t)b * AN + wbase[wv] + pre] = a;
    }
}

// ---------- hist1: L1 cell histogram over dense candidate list ----------
__global__ __launch_bounds__(256) void hist1_kernel(
    const float* __restrict__ conf, const int* __restrict__ cand,
    const unsigned* __restrict__ cand_cnt, const Chain* __restrict__ chains,
    unsigned* __restrict__ cnt1)
{
    int b = blockIdx.y, tid = threadIdx.x;
    if (!chains[b].active) return;
    unsigned vbits = chains[b].ve >> 1;
    unsigned m = min(cand_cnt[b], (unsigned)AN);
    __shared__ unsigned h[NBA];
    for (int i = tid; i < NBA; i += 256) h[i] = 0u;
    __syncthreads();
    for (unsigned i = blockIdx.x * 256u + tid; i < m; i += 32u * 256u) {
        int a = cand[(size_t)b * AN + i];
        size_t idx = (size_t)b * AN + a;
        float c[CN];
        float inv = row_prep(conf + idx * CN, c);
#pragma unroll
        for (int j = 0; j < CN; ++j) {
            float fo = cell_focal(c[j], inv, false);
            unsigned bits = focal_bits(fo);
            if (bits >= vbits) atomicAdd(&h[bits >> 20], 1u);
        }
    }
    __syncthreads();
    for (int i = tid; i < NBA; i += 256) {
        unsigned v = h[i];
        if (v) atomicAdd(&cnt1[b * NBA + i], v);
    }
}

// ---------- refine2 (+inline select1): sumAbove + boundary-bin value list ----------
__global__ __launch_bounds__(256) void refine2_kernel(
    const float* __restrict__ conf, const int* __restrict__ cand,
    const unsigned* __restrict__ cand_cnt, const unsigned* __restrict__ cnt1,
    Chain* __restrict__ chains,
    float* __restrict__ list, unsigned* __restrict__ listCnt)
{
    int b = blockIdx.y, tid = threadIdx.x;
    if (!chains[b].active) return;
    unsigned k = chains[b].k;
    // inline select1: find level-1 boundary bin from cnt1
    const unsigned* cnt = cnt1 + (size_t)b * NBA;
    unsigned lc[8], ccnt = 0;
#pragma unroll
    for (int i = 0; i < 8; ++i) { lc[i] = cnt[tid * 8 + i]; ccnt += lc[i]; }
    __shared__ unsigned scnt[256];
    __shared__ unsigned sb1, srem;
    if (tid == 0) { sb1 = 0; srem = 0; }
    scnt[tid] = ccnt;
    __syncthreads();
    for (int off = 1; off < 256; off <<= 1) {
        unsigned vc = (tid + off < 256) ? scnt[tid + off] : 0u;
        __syncthreads();
        scnt[tid] += vc;
        __syncthreads();
    }
    unsigned total = scnt[0];
    unsigned aboveCnt = (tid < 255) ? scnt[tid + 1] : 0u;
    unsigned r = min(k, total);
    if (r > 0 && aboveCnt < r && aboveCnt + ccnt >= r) {
        unsigned a2 = aboveCnt;
        for (int i = 7; i >= 0; --i) {
            unsigned bc = lc[i];
            if (a2 + bc >= r) { sb1 = (unsigned)(tid * 8 + i); srem = r - a2; break; }
            a2 += bc;
        }
    }
    __syncthreads();
    unsigned b1 = sb1, rem = srem;
    if (blockIdx.x == 0 && tid == 0) { chains[b].b1 = b1; chains[b].rem = rem; }

    unsigned m = min(cand_cnt[b], (unsigned)AN);
    double sA = 0.0;
    for (unsigned i = blockIdx.x * 256u + tid; i < m; i += 32u * 256u) {
        int a = cand[(size_t)b * AN + i];
        size_t idx = (size_t)b * AN + a;
        float c[CN];
        float inv = row_prep(conf + idx * CN, c);
#pragma unroll
        for (int j = 0; j < CN; ++j) {
            float fo = cell_focal(c[j], inv, false);
            unsigned bits = focal_bits(fo);
            unsigned hi = bits >> 20;
            if (hi > b1) sA += (double)fo;
            else if (hi == b1) {
                unsigned p = atomicAdd(&listCnt[b], 1u);
                if (p < (unsigned)AN) list[(size_t)b * AN + p] = fo;
            }
        }
    }
#pragma unroll
    for (int off = 32; off; off >>= 1) sA += __shfl_down(sA, off, 64);
    __shared__ double sred[4];
    int wv = tid >> 6, ln = tid & 63;
    if (ln == 0) sred[wv] = sA;
    __syncthreads();
    if (tid == 0) {
        double tt = sred[0] + sred[1] + sred[2] + sred[3];
        if (tt != 0.0) atomicAdd(&chains[b].sumAbove, tt);
    }
}

// ---------- selectF: exact top-rem sum within boundary bin (1 block/image) ----------
__global__ __launch_bounds__(256) void selectF_kernel(
    const float* __restrict__ list, const unsigned* __restrict__ listCnt,
    Chain* __restrict__ chains)
{
    int b = blockIdx.x, tid = threadIdx.x;
    Chain* ch = &chains[b];
    if (!ch->active) return;
    unsigned rem = ch->rem;
    unsigned n = min(listCnt[b], (unsigned)AN);
    const float* L = list + (size_t)b * AN;
    if (rem == 0 || n == 0) { if (tid == 0) ch->topk = ch->sumAbove; return; }
    // pass 1: 4096-bin histogram of (bits>>8)&0xFFF
    __shared__ unsigned h12[4096];
    for (int i = tid; i < 4096; i += 256) h12[i] = 0u;
    __syncthreads();
    for (unsigned i = tid; i < n; i += 256)
        atomicAdd(&h12[(__float_as_uint(L[i]) >> 8) & 0xFFFu], 1u);
    __syncthreads();
    unsigned lc[16], ccnt = 0;
#pragma unroll
    for (int i = 0; i < 16; ++i) { lc[i] = h12[tid * 16 + i]; ccnt += lc[i]; }
    __shared__ unsigned scnt[256];
    __shared__ unsigned sb2, srem2;
    if (tid == 0) { sb2 = 0; srem2 = 0; }
    scnt[tid] = ccnt;
    __syncthreads();
    for (int off = 1; off < 256; off <<= 1) {
        unsigned vc = (tid + off < 256) ? scnt[tid + off] : 0u;
        __syncthreads();
        scnt[tid] += vc;
        __syncthreads();
    }
    unsigned above = (tid < 255) ? scnt[tid + 1] : 0u;
    unsigned r = min(rem, scnt[0]);
    if (above < r && above + ccnt >= r) {
        unsigned a2 = above;
        for (int i = 15; i >= 0; --i) {
            unsigned bc = lc[i];
            if (a2 + bc >= r) { sb2 = (unsigned)(tid * 16 + i); srem2 = r - a2; break; }
            a2 += bc;
        }
    }
    __syncthreads();
    unsigned b2 = sb2, rem2 = srem2;
    // pass 2: mid-sum (sub > b2) + 256-bin count of (sub == b2)
    __shared__ unsigned h8[256];
    h8[tid] = 0u;
    __syncthreads();
    double sMid = 0.0;
    for (unsigned i = tid; i < n; i += 256) {
        float v = L[i];
        unsigned bits = __float_as_uint(v);
        unsigned sub = (bits >> 8) & 0xFFFu;
        if (sub > b2) sMid += (double)v;
        else if (sub == b2) atomicAdd(&h8[bits & 0xFFu], 1u);
    }
    __syncthreads();
    unsigned c8 = h8[tid];
    __shared__ unsigned s8[256];
    __shared__ unsigned sb3, srem3;
    if (tid == 0) { sb3 = 0; srem3 = 0; }
    s8[tid] = c8;
    __syncthreads();
    for (int off = 1; off < 256; off <<= 1) {
        unsigned vc = (tid + off < 256) ? s8[tid + off] : 0u;
        __syncthreads();
        s8[tid] += vc;
        __syncthreads();
    }
    unsigned above8 = (tid < 255) ? s8[tid + 1] : 0u;
    if (above8 < rem2 && above8 + c8 >= rem2) { sb3 = (unsigned)tid; srem3 = rem2 - above8; }
    __syncthreads();
    unsigned b3 = sb3, rem3 = srem3;
    // pass 3: sum of (sub == b2, low > b3)
    double s3 = 0.0;
    for (unsigned i = tid; i < n; i += 256) {
        float v = L[i];
        unsigned bits = __float_as_uint(v);
        if (((bits >> 8) & 0xFFFu) == b2 && (bits & 0xFFu) > b3) s3 += (double)v;
    }
    double tot = sMid + s3;
#pragma unroll
    for (int off = 32; off; off >>= 1) tot += __shfl_down(tot, off, 64);
    __shared__ double sred[4];
    int wv = tid >> 6, ln = tid & 63;
    if (ln == 0) sred[wv] = tot;
    __syncthreads();
    if (tid == 0) {
        double totAll = sred[0] + sred[1] + sred[2] + sred[3];
        unsigned vbits = (ch->b1 << 20) | (b2 << 8) | b3;
        ch->topk = ch->sumAbove + totAll + (double)rem3 * (double)__uint_as_float(vbits);
    }
}

// ---------- finalize ----------
__global__ void finalize_kernel(const Acc* __restrict__ acc,
                                const Chain* __restrict__ chains,
                                float* __restrict__ out)
{
    __shared__ double cl[BN], bl[BN];
    int t = threadIdx.x;
    if (t < BN) {
        unsigned np = acc[t].np, nn = acc[t].nn;
        double pos_sum = acc[t].pos_sum, bbox_sum = acc[t].bbox_sum;
        unsigned npc = max(np, 1u);
        double conf;
        if (nn > 0) {
            unsigned k = min(3u * np, nn);
            conf = (pos_sum + chains[t].topk) / (double)max(np + k, 1u);
        } else {
            conf = pos_sum / (double)npc;
        }
        cl[t] = conf;
        bl[t] = bbox_sum / (double)npc;
    }
    __syncthreads();
    if (t == 0) {
        double cs = 0, bs = 0;
        for (int i = 0; i < BN; ++i) { cs += cl[i]; bs += bl[i]; }
        cs /= BN; bs /= BN;
        out[0] = (float)(cs + bs);
        out[1] = (float)cs;
        out[2] = (float)bs;
    }
}

extern "C" void kernel_launch(void* const* d_in, const int* in_sizes, int n_in,
                              void* d_out, int out_size, void* d_ws, size_t ws_size,
                              hipStream_t stream)
{
    (void)in_sizes; (void)n_in; (void)out_size; (void)ws_size;
    const float*  conf    = (const float*)d_in[0];
    const float4* bboxp   = (const float4*)d_in[1];
    const float4* anchors = (const float4*)d_in[2];
    const float4* tboxes  = (const float4*)d_in[3];
    const int*    tlabels = (const int*)d_in[4];
    float* out = (float*)d_out;
    char* ws = (char*)d_ws;
    size_t off = 0;
    auto alloc = [&](size_t bytes) -> void* {
        void* p = (void*)(ws + off);
        off = (off + bytes + 255) & ~(size_t)255;
        return p;
    };
    unsigned* maxb     = (unsigned*)alloc((size_t)BN * AN * 4);
    int*      cand     = (int*)alloc((size_t)BN * AN * 4);
    float*    list     = (float*)alloc((size_t)BN * AN * 4);
    BlockAcc* blockAcc = (BlockAcc*)alloc((size_t)BN * 256 * sizeof(BlockAcc));
    Acc*      acc      = (Acc*)alloc(BN * sizeof(Acc));
    size_t zstart = off;
    unsigned long long* gbest = (unsigned long long*)alloc((size_t)BN * TN * 8);
    Chain*    chains   = (Chain*)alloc(BN * sizeof(Chain));
    unsigned* ahist    = (unsigned*)alloc((size_t)BN * NBA * 4);
    unsigned* cand_cnt = (unsigned*)alloc((size_t)BN * 4);
    unsigned* cnt1     = (unsigned*)alloc((size_t)BN * NBA * 4);
    unsigned* listCnt  = (unsigned*)alloc((size_t)BN * 4);
    size_t zbytes = off - zstart;
    hipMemsetAsync(ws + zstart, 0, zbytes, stream);

    dim3 gridA(AN / 256, BN);
    dim3 gridH(32, BN);
    main_kernel<<<gridA, 256, 0, stream>>>(conf, bboxp, anchors, tboxes, tlabels,
                                           gbest, ahist, maxb, blockAcc);
    force_sel0_kernel<<<BN, 256, 0, stream>>>(conf, bboxp, anchors, tboxes, tlabels,
                                              gbest, blockAcc, ahist, maxb, acc, chains);
    compact_kernel<<<gridA, 256, 0, stream>>>(maxb, chains, cand, cand_cnt);
    hist1_kernel<<<gridH, 256, 0, stream>>>(conf, cand, cand_cnt, chains, cnt1);
    refine2_kernel<<<gridH, 256, 0, stream>>>(conf, cand, cand_cnt, cnt1, chains, list, listCnt);
    selectF_kernel<<<BN, 256, 0, stream>>>(list, listCnt, chains);
    finalize_kernel<<<1, 64, 0, stream>>>(acc, chains, out);
}

// Round 7
// 288.580 us; speedup vs baseline: 1.2587x; 1.2587x over previous
//
#include <hip/hip_runtime.h>

// DetectionLoss: B=16, A=65536, T=32, C=21.
// R7: main = R5 proven structure (phase-2 recompute) + rcp IoU + packed anchor
// hist. refine2 = wave-aggregated boundary-list emission (no per-cell global
// atomics). 8 graph nodes: memset, main, force+select0, compact, hist1,
// refine2(+inline select1), selectF, finalize.

#define AN 65536
#define BN 16
#define TN 32
#define CN 21
#define NBA 2048   // anchor/cell L1 bins = focal bits >> 20

struct Acc   { double pos_sum; double bbox_sum; unsigned np; unsigned nn; };
struct Chain { double sumAbove; double topk; unsigned active; unsigned k; unsigned ve;
               unsigned b1; unsigned rem; };
struct BlockAcc { float pos_sum; float bbox_sum; unsigned np; unsigned nn; };

// ---------- shared math: bit-identical across kernels (_rn-pinned, shared fns) ----------
__device__ __forceinline__ float box_area(float4 B) {
    return __fmul_rn(__fsub_rn(B.z, B.x), __fsub_rn(B.w, B.y));
}
__device__ __forceinline__ float iou_rcp(float4 A, float aa, float4 T, float ta) {
    float x1 = fmaxf(A.x, T.x), y1 = fmaxf(A.y, T.y);
    float x2 = fminf(A.z, T.z), y2 = fminf(A.w, T.w);
    float inter = __fmul_rn(fmaxf(__fsub_rn(x2, x1), 0.f), fmaxf(__fsub_rn(y2, y1), 0.f));
    float den = __fadd_rn(__fsub_rn(__fadd_rn(aa, ta), inter), 1e-6f);
    return __fmul_rn(inter, __builtin_amdgcn_rcpf(den));
}
__device__ __forceinline__ float row_prep(const float* __restrict__ row, float* __restrict__ c) {
#pragma unroll
    for (int j = 0; j < CN; ++j) c[j] = row[j];
    float m1[10];
#pragma unroll
    for (int j = 0; j < 10; ++j) m1[j] = fmaxf(c[j], c[j + 10]);
    float m2[5];
#pragma unroll
    for (int j = 0; j < 5; ++j) m2[j] = fmaxf(m1[j], m1[j + 5]);
    float ma = fmaxf(m2[0], m2[1]), mb = fmaxf(m2[2], m2[3]);
    float m = fmaxf(fmaxf(ma, mb), fmaxf(m2[4], c[20]));
#pragma unroll
    for (int j = 0; j < CN; ++j) c[j] = __expf(__fsub_rn(c[j], m));
    float s1[10];
#pragma unroll
    for (int j = 0; j < 10; ++j) s1[j] = __fadd_rn(c[j], c[j + 10]);
    float s2[5];
#pragma unroll
    for (int j = 0; j < 5; ++j) s2[j] = __fadd_rn(s1[j], s1[j + 5]);
    float sa = __fadd_rn(s2[0], s2[1]), sb = __fadd_rn(s2[2], s2[3]);
    float s = __fadd_rn(__fadd_rn(sa, sb), __fadd_rn(s2[4], c[20]));
    return __builtin_amdgcn_rcpf(s);
}
__device__ __forceinline__ float cell_focal(float cexp, float inv, bool cellpos) {
    float p = __fmul_rn(cexp, inv);
    float pt = cellpos ? p : __fsub_rn(1.0f, p);
    float af = cellpos ? 0.25f : 0.75f;
    float om = __fsub_rn(1.0f, pt);
    float lg = __logf(fmaxf(pt, 1e-6f));
    return __fmul_rn(__fmul_rn(__fmul_rn(-af, om), om), lg);
}
__device__ __forceinline__ unsigned focal_bits(float fo) {
    unsigned bits = __float_as_uint(fo);
    if (bits == 0x80000000u) bits = 0u;   // canonicalize -0.0
    return bits;
}
__device__ __forceinline__ float bbox_per(float4 b1, float4 b2) {
    float x1 = fmaxf(b1.x, b2.x), y1 = fmaxf(b1.y, b2.y);
    float x2 = fminf(b1.z, b2.z), y2 = fminf(b1.w, b2.w);
    float inter = fmaxf(x2 - x1, 0.f) * fmaxf(y2 - y1, 0.f);
    float a1 = (b1.z - b1.x) * (b1.w - b1.y);
    float a2 = (b2.z - b2.x) * (b2.w - b2.y);
    float un = a1 + a2 - inter;
    float iou = inter / (un + 1e-6f);
    float ex1 = fminf(b1.x, b2.x), ey1 = fminf(b1.y, b2.y);
    float ex2 = fmaxf(b1.z, b2.z), ey2 = fmaxf(b1.w, b2.w);
    float enc = (ex2 - ex1) * (ey2 - ey1);
    float giou = iou - (enc - un) / (enc + 1e-6f);
    float gl = 1.0f - giou;
    float l1 = 0.f, d, ad;
    d = b1.x - b2.x; ad = fabsf(d); l1 += (ad < 1.f) ? (0.5f * d * d) : (ad - 0.5f);
    d = b1.y - b2.y; ad = fabsf(d); l1 += (ad < 1.f) ? (0.5f * d * d) : (ad - 0.5f);
    d = b1.z - b2.z; ad = fabsf(d); l1 += (ad < 1.f) ? (0.5f * d * d) : (ad - 0.5f);
    d = b1.w - b2.w; ad = fabsf(d); l1 += (ad < 1.f) ? (0.5f * d * d) : (ad - 0.5f);
    return gl + 0.5f * (l1 * 0.25f);
}

// ---------- fused main: match + force-argmax + focal + anchor hist ----------
__global__ __launch_bounds__(256) void main_kernel(
    const float* __restrict__ conf, const float4* __restrict__ bboxp,
    const float4* __restrict__ anchors, const float4* __restrict__ tboxes,
    const int* __restrict__ tlabels,
    unsigned long long* __restrict__ gbest,
    unsigned* __restrict__ ahist, unsigned* __restrict__ maxb,
    BlockAcc* __restrict__ blockAcc)
{
    __shared__ float4 tbS[TN];
    __shared__ float4 aS[256];             // 4 KB
    __shared__ int tlS[TN];
    __shared__ float taS[TN];
    __shared__ unsigned ahp[NBA / 2];      // 4 KB packed (2 bins/u32)
    __shared__ float pbV[TN][8];
    __shared__ int   pbA[TN][8];
    __shared__ float rF[2][4];
    __shared__ unsigned rI[2][4];
    int b = blockIdx.y, tid = threadIdx.x;
    int a = blockIdx.x * 256 + tid;
    for (int i = tid; i < NBA / 2; i += 256) ahp[i] = 0u;
    if (tid < TN) {
        float4 T = tboxes[b * TN + tid];
        tbS[tid] = T; tlS[tid] = tlabels[b * TN + tid]; taS[tid] = box_area(T);
    }
    float4 ab = anchors[a];
    aS[tid] = ab;
    float aa = box_area(ab);
    __syncthreads();

    // phase 1: per-anchor max IoU over targets
    float best = -1.0f; int bt = 0;
#pragma unroll
    for (int t = 0; t < TN; ++t) {
        float iou = iou_rcp(ab, aa, tbS[t], taS[t]);
        if (iou > best) { best = iou; bt = t; }   // strict >: first-occurrence argmax
    }

    // phase 2: per-target best anchor within block (recompute from LDS, rcp)
    {
        int t = tid & 31, pp = tid >> 5;
        float4 T = tbS[t];
        float ta = taS[t];
        float bv = -1.f; int ba = 0;
#pragma unroll
        for (int i2 = 0; i2 < 32; ++i2) {
            int r = pp * 32 + i2;
            float4 A = aS[r];
            float iou = iou_rcp(A, box_area(A), T, ta);
            if (iou > bv) { bv = iou; ba = r; }
        }
        pbV[t][pp] = bv; pbA[t][pp] = ba;
    }
    __syncthreads();
    if (tid < TN) {
        float bv = -1.f; int ba = 0;
#pragma unroll
        for (int pp = 0; pp < 8; ++pp) {
            float v = pbV[tid][pp];
            if (v > bv) { bv = v; ba = pbA[tid][pp]; }
        }
        unsigned ga = blockIdx.x * 256 + (unsigned)ba;
        unsigned long long key =
            (((unsigned long long)__float_as_uint(bv)) << 32) | (unsigned long long)(unsigned)(~ga);
        atomicMax(&gbest[b * TN + tid], key);   // tie -> smaller anchor idx
    }

    // phase 3: focal (threshold classification; forced anchors fixed later)
    size_t idx = (size_t)b * AN + a;
    bool posA = best >= 0.5f;
    bool negA = best < 0.4f;
    float fs = 0.f, bper = 0.f;
    unsigned mbenc = 0u;
    if (posA || negA) {
        int label = posA ? tlS[bt] : -1;
        float c[CN];
        float inv = row_prep(conf + idx * CN, c);
        unsigned mb = 0u;
#pragma unroll
        for (int j = 0; j < CN; ++j) {
            float fo = cell_focal(c[j], inv, j == label);
            fs += fo;
            mb = max(mb, focal_bits(fo));
        }
        if (negA) {
            mbenc = (mb << 1) | 1u;
            unsigned bin = mb >> 20;
            atomicAdd(&ahp[bin >> 1], 1u << ((bin & 1) << 4));
        } else {
            bper = bbox_per(bboxp[idx], tbS[bt]);
        }
    }
    maxb[idx] = mbenc;

    // block reduce {pos_sum, bbox_sum, np, nn} -> plain store
    float vpos = posA ? fs : 0.f, vb = bper;
    unsigned inp = posA ? 1u : 0u, inn = negA ? 1u : 0u;
#pragma unroll
    for (int off = 32; off; off >>= 1) {
        vpos += __shfl_down(vpos, off, 64);
        vb   += __shfl_down(vb,   off, 64);
        inp  += __shfl_down(inp,  off, 64);
        inn  += __shfl_down(inn,  off, 64);
    }
    int wv = tid >> 6, ln = tid & 63;
    if (ln == 0) { rF[0][wv] = vpos; rF[1][wv] = vb; rI[0][wv] = inp; rI[1][wv] = inn; }
    __syncthreads();
    if (tid == 0) {
        BlockAcc ba2;
        ba2.pos_sum = rF[0][0] + rF[0][1] + rF[0][2] + rF[0][3];
        ba2.bbox_sum = rF[1][0] + rF[1][1] + rF[1][2] + rF[1][3];
        ba2.np = rI[0][0] + rI[0][1] + rI[0][2] + rI[0][3];
        ba2.nn = rI[1][0] + rI[1][1] + rI[1][2] + rI[1][3];
        blockAcc[b * 256 + blockIdx.x] = ba2;
    }
    for (int i = tid; i < NBA / 2; i += 256) {
        unsigned v = ahp[i];
        if (v) {
            if (v & 0xFFFFu) atomicAdd(&ahist[b * NBA + 2 * i], v & 0xFFFFu);
            if (v >> 16)     atomicAdd(&ahist[b * NBA + 2 * i + 1], v >> 16);
        }
    }
}

// ---------- force-match fix + totals + threshold (merged, 1 block/image) ----------
__global__ __launch_bounds__(256) void force_sel0_kernel(
    const float* __restrict__ conf, const float4* __restrict__ bboxp,
    const float4* __restrict__ anchors, const float4* __restrict__ tboxes,
    const int* __restrict__ tlabels,
    const unsigned long long* __restrict__ gbest,
    const BlockAcc* __restrict__ blockAcc,
    unsigned* __restrict__ ahist, unsigned* __restrict__ maxb,
    Acc* __restrict__ acc, Chain* __restrict__ chains)
{
    __shared__ unsigned gaS[TN];
    __shared__ float4 tbS[TN];
    __shared__ int tlS[TN];
    __shared__ float taS[TN];
    __shared__ float dps[TN], dbb[TN];
    __shared__ int dnp[TN], dnn[TN];
    int b = blockIdx.x, tid = threadIdx.x;
    if (tid < TN) {
        gaS[tid] = ~(unsigned)(gbest[b * TN + tid] & 0xFFFFFFFFull);
        float4 T = tboxes[b * TN + tid];
        tbS[tid] = T; tlS[tid] = tlabels[b * TN + tid]; taS[tid] = box_area(T);
        dps[tid] = 0.f; dbb[tid] = 0.f; dnp[tid] = 0; dnn[tid] = 0;
    }
    __syncthreads();
    if (tid < TN) {
        bool doit = true;
        unsigned ga = gaS[tid];
        for (int u = 0; u < tid; ++u) if (gaS[u] == ga) doit = false;   // dedupe
        if (doit) {
            size_t idx = (size_t)b * AN + ga;
            float4 ab = anchors[ga];
            float aa = box_area(ab);
            float best = -1.f; int bt = 0;
#pragma unroll
            for (int t = 0; t < TN; ++t) {
                float iou = iou_rcp(ab, aa, tbS[t], taS[t]);   // bit-identical to main
                if (iou > best) { best = iou; bt = t; }
            }
            if (best < 0.5f) {   // not already pos via threshold
                int label = tlS[bt];
                float c[CN];
                float inv = row_prep(conf + idx * CN, c);
                float fsv = 0.f;
#pragma unroll
                for (int j = 0; j < CN; ++j) fsv += cell_focal(c[j], inv, j == label);
                dps[tid] = fsv;
                dbb[tid] = bbox_per(bboxp[idx], tbS[bt]);
                dnp[tid] = 1;
                if (best < 0.4f) {   // was counted neg: undo
                    unsigned mbv = maxb[idx];
                    atomicSub(&ahist[b * NBA + (mbv >> 21)], 1u);
                    maxb[idx] = 0u;
                    dnn[tid] = -1;
                }
            }
        }
    }
    __threadfence();
    __syncthreads();

    // totals
    BlockAcc ba = blockAcc[b * 256 + tid];
    double ps = (double)ba.pos_sum, bs = (double)ba.bbox_sum;
    unsigned np = ba.np, nn = ba.nn;
#pragma unroll
    for (int off = 32; off; off >>= 1) {
        ps += __shfl_down(ps, off, 64);
        bs += __shfl_down(bs, off, 64);
        np += __shfl_down(np, off, 64);
        nn += __shfl_down(nn, off, 64);
    }
    __shared__ double sps[4], sbs[4];
    __shared__ unsigned snp[4], snn[4];
    __shared__ unsigned s_nn, s_np;
    int wv = tid >> 6, ln = tid & 63;
    if (ln == 0) { sps[wv] = ps; sbs[wv] = bs; snp[wv] = np; snn[wv] = nn; }
    __syncthreads();
    if (tid == 0) {
        double dp = 0, db = 0; int cp = 0, cn = 0;
        for (int i = 0; i < TN; ++i) { dp += dps[i]; db += dbb[i]; cp += dnp[i]; cn += dnn[i]; }
        Acc A;
        A.pos_sum = sps[0] + sps[1] + sps[2] + sps[3] + dp;
        A.bbox_sum = sbs[0] + sbs[1] + sbs[2] + sbs[3] + db;
        A.np = (unsigned)((int)(snp[0] + snp[1] + snp[2] + snp[3]) + cp);
        A.nn = (unsigned)((int)(snn[0] + snn[1] + snn[2] + snn[3]) + cn);
        acc[b] = A;
        s_np = A.np; s_nn = A.nn;
    }
    __syncthreads();
    unsigned nnT = s_nn, npT = s_np;
    if (nnT == 0) return;   // chain inactive; finalize uses pos-only branch
    unsigned k = min(3u * npT, nnT);

    // anchor-max threshold scan over 2048 bins
    const unsigned* h = ahist + b * NBA;
    unsigned lc[8], ccnt = 0;
#pragma unroll
    for (int i = 0; i < 8; ++i) { lc[i] = h[tid * 8 + i]; ccnt += lc[i]; }
    __shared__ unsigned scnt[256];
    scnt[tid] = ccnt;
    __syncthreads();
    for (int off = 1; off < 256; off <<= 1) {
        unsigned vc = (tid + off < 256) ? scnt[tid + off] : 0u;
        __syncthreads();
        scnt[tid] += vc;
        __syncthreads();
    }
    unsigned aboveCnt = (tid < 255) ? scnt[tid + 1] : 0u;
    if (aboveCnt < k && aboveCnt + ccnt >= k) {
        unsigned acc2 = aboveCnt;
        for (int i = 7; i >= 0; --i) {
            if (acc2 + lc[i] >= k) {
                unsigned bin = (unsigned)(tid * 8 + i);
                chains[b].active = 1;
                chains[b].k = k;
                chains[b].ve = (bin << 21) | 1u;   // encoded threshold in maxb space
                break;
            }
            acc2 += lc[i];
        }
    }
}

// ---------- compact: candidate anchors (coalesced maxb read, ballot) ----------
__global__ __launch_bounds__(256) void compact_kernel(
    const unsigned* __restrict__ maxb, const Chain* __restrict__ chains,
    int* __restrict__ cand, unsigned* __restrict__ cand_cnt)
{
    int b = blockIdx.y, tid = threadIdx.x;
    if (!chains[b].active) return;
    unsigned ve = chains[b].ve;
    int a = blockIdx.x * 256 + tid;
    size_t idx = (size_t)b * AN + a;
    bool q = (maxb[idx] >= ve);
    unsigned long long msk = __ballot(q);
    int wv = tid >> 6, ln = tid & 63;
    __shared__ unsigned wbase[4];
    __shared__ unsigned nonzero;
    if (tid == 0) nonzero = 0;
    __syncthreads();
    if (ln == 0) { wbase[wv] = (unsigned)__popcll(msk); if (msk) atomicOr(&nonzero, 1u); }
    __syncthreads();
    if (!nonzero) return;
    if (tid == 0) {
        unsigned tot = wbase[0] + wbase[1] + wbase[2] + wbase[3];
        unsigned base = atomicAdd(&cand_cnt[b], tot);
        unsigned run = base;
        for (int w = 0; w < 4; ++w) { unsigned t2 = wbase[w]; wbase[w] = run; run += t2; }
    }
    __syncthreads();
    if (q) {
        unsigned pre = (unsigned)__popcll(msk & ((ln == 63) ? ~0ULL >> 1 : ((1ULL << (ln + 1)) - 1ULL) >> 1));
        cand[(size_t)b * AN + wbase[wv] + pre] = a;
    }
}

// ---------- hist1: L1 cell histogram over dense candidate list ----------
__global__ __launch_bounds__(256) void hist1_kernel(
    const float* __restrict__ conf, const int* __restrict__ cand,
    const unsigned* __restrict__ cand_cnt, const Chain* __restrict__ chains,
    unsigned* __restrict__ cnt1)
{
    int b = blockIdx.y, tid = threadIdx.x;
    if (!chains[b].active) return;
    unsigned vbits = chains[b].ve >> 1;
    unsigned m = min(cand_cnt[b], (unsigned)AN);
    __shared__ unsigned h[NBA];
    for (int i = tid; i < NBA; i += 256) h[i] = 0u;
    __syncthreads();
    for (unsigned i = blockIdx.x * 256u + tid; i < m; i += 32u * 256u) {
        int a = cand[(size_t)b * AN + i];
        size_t idx = (size_t)b * AN + a;
        float c[CN];
        float inv = row_prep(conf + idx * CN, c);
#pragma unroll
        for (int j = 0; j < CN; ++j) {
            float fo = cell_focal(c[j], inv, false);
            unsigned bits = focal_bits(fo);
            if (bits >= vbits) atomicAdd(&h[bits >> 20], 1u);
        }
    }
    __syncthreads();
    for (int i = tid; i < NBA; i += 256) {
        unsigned v = h[i];
        if (v) atomicAdd(&cnt1[b * NBA + i], v);
    }
}

// ---------- refine2 (+inline select1): sumAbove + wave-aggregated boundary list ----------
__global__ __launch_bounds__(256) void refine2_kernel(
    const float* __restrict__ conf, const int* __restrict__ cand,
    const unsigned* __restrict__ cand_cnt, const unsigned* __restrict__ cnt1,
    Chain* __restrict__ chains,
    float* __restrict__ list, unsigned* __restrict__ listCnt)
{
    int b = blockIdx.y, tid = threadIdx.x;
    if (!chains[b].active) return;
    unsigned k = chains[b].k;
    // inline select1: find level-1 boundary bin from cnt1
    const unsigned* cnt = cnt1 + (size_t)b * NBA;
    unsigned lc[8], ccnt = 0;
#pragma unroll
    for (int i = 0; i < 8; ++i) { lc[i] = cnt[tid * 8 + i]; ccnt += lc[i]; }
    __shared__ unsigned scnt[256];
    __shared__ unsigned sb1, srem;
    if (tid == 0) { sb1 = 0; srem = 0; }
    scnt[tid] = ccnt;
    __syncthreads();
    for (int off = 1; off < 256; off <<= 1) {
        unsigned vc = (tid + off < 256) ? scnt[tid + off] : 0u;
        __syncthreads();
        scnt[tid] += vc;
        __syncthreads();
    }
    unsigned total = scnt[0];
    unsigned aboveCnt = (tid < 255) ? scnt[tid + 1] : 0u;
    unsigned r = min(k, total);
    if (r > 0 && aboveCnt < r && aboveCnt + ccnt >= r) {
        unsigned a2 = aboveCnt;
        for (int i = 7; i >= 0; --i) {
            unsigned bc = lc[i];
            if (a2 + bc >= r) { sb1 = (unsigned)(tid * 8 + i); srem = r - a2; break; }
            a2 += bc;
        }
    }
    __syncthreads();
    unsigned b1 = sb1, rem = srem;
    if (blockIdx.x == 0 && tid == 0) { chains[b].b1 = b1; chains[b].rem = rem; }

    unsigned m = min(cand_cnt[b], (unsigned)AN);
    int wv = tid >> 6, ln = tid & 63;
    __shared__ float wbuf[4][1344];   // per-wave staging (64 lanes x 21 cells max)
    double sA = 0.0;
    unsigned nIter = (m + 8191u) >> 13;
    for (unsigned it = 0; it < nIter; ++it) {
        unsigned i = (it << 13) + blockIdx.x * 256u + (unsigned)tid;
        bool valid = i < m;
        int a = valid ? cand[(size_t)b * AN + i] : 0;
        size_t idx = (size_t)b * AN + a;
        float c[CN];
        float inv = row_prep(conf + idx * CN, c);
        unsigned wc = 0;
#pragma unroll
        for (int j = 0; j < CN; ++j) {
            float fo = cell_focal(c[j], inv, false);
            unsigned bits = focal_bits(fo);
            unsigned hi = bits >> 20;
            if (valid && hi > b1) sA += (double)fo;
            bool hit = valid && (hi == b1);
            unsigned long long msk = __ballot(hit);
            if (hit) {
                unsigned pre = __builtin_amdgcn_mbcnt_hi(
                    (unsigned)(msk >> 32),
                    __builtin_amdgcn_mbcnt_lo((unsigned)msk, 0u));
                wbuf[wv][wc + pre] = fo;
            }
            wc += (unsigned)__popcll(msk);   // wave-uniform
        }
        if (wc) {
            unsigned base = 0;
            if (ln == 0) base = atomicAdd(&listCnt[b], wc);
            base = __shfl(base, 0, 64);
            for (unsigned i2 = (unsigned)ln; i2 < wc; i2 += 64u)
                list[(size_t)b * AN + base + i2] = wbuf[wv][i2];
        }
    }
#pragma unroll
    for (int off = 32; off; off >>= 1) sA += __shfl_down(sA, off, 64);
    __shared__ double sred[4];
    if (ln == 0) sred[wv] = sA;
    __syncthreads();
    if (tid == 0) {
        double tt = sred[0] + sred[1] + sred[2] + sred[3];
        if (tt != 0.0) atomicAdd(&chains[b].sumAbove, tt);
    }
}

// ---------- selectF: exact top-rem sum within boundary bin (1 block/image) ----------
__global__ __launch_bounds__(256) void selectF_kernel(
    const float* __restrict__ list, const unsigned* __restrict__ listCnt,
    Chain* __restrict__ chains)
{
    int b = blockIdx.x, tid = threadIdx.x;
    Chain* ch = &chains[b];
    if (!ch->active) return;
    unsigned rem = ch->rem;
    unsigned n = min(listCnt[b], (unsigned)AN);
    const float* L = list + (size_t)b * AN;
    if (rem == 0 || n == 0) { if (tid == 0) ch->topk = ch->sumAbove; return; }
    // pass 1: 4096-bin histogram of (bits>>8)&0xFFF
    __shared__ unsigned h12[4096];
    for (int i = tid; i < 4096; i += 256) h12[i] = 0u;
    __syncthreads();
    for (unsigned i = tid; i < n; i += 256)
        atomicAdd(&h12[(__float_as_uint(L[i]) >> 8) & 0xFFFu], 1u);
    __syncthreads();
    unsigned lc[16], ccnt = 0;
#pragma unroll
    for (int i = 0; i < 16; ++i) { lc[i] = h12[tid * 16 + i]; ccnt += lc[i]; }
    __shared__ unsigned scnt[256];
    __shared__ unsigned sb2, srem2;
    if (tid == 0) { sb2 = 0; srem2 = 0; }
    scnt[tid] = ccnt;
    __syncthreads();
    for (int off = 1; off < 256; off <<= 1) {
        unsigned vc = (tid + off < 256) ? scnt[tid + off] : 0u;
        __syncthreads();
        scnt[tid] += vc;
        __syncthreads();
    }
    unsigned above = (tid < 255) ? scnt[tid + 1] : 0u;
    unsigned r = min(rem, scnt[0]);
    if (above < r && above + ccnt >= r) {
        unsigned a2 = above;
        for (int i = 15; i >= 0; --i) {
            unsigned bc = lc[i];
            if (a2 + bc >= r) { sb2 = (unsigned)(tid * 16 + i); srem2 = r - a2; break; }
            a2 += bc;
        }
    }
    __syncthreads();
    unsigned b2 = sb2, rem2 = srem2;
    // pass 2: mid-sum (sub > b2) + 256-bin count of (sub == b2)
    __shared__ unsigned h8[256];
    h8[tid] = 0u;
    __syncthreads();
    double sMid = 0.0;
    for (unsigned i = tid; i < n; i += 256) {
        float v = L[i];
        unsigned bits = __float_as_uint(v);
        unsigned sub = (bits >> 8) & 0xFFFu;
        if (sub > b2) sMid += (double)v;
        else if (sub == b2) atomicAdd(&h8[bits & 0xFFu], 1u);
    }
    __syncthreads();
    unsigned c8 = h8[tid];
    __shared__ unsigned s8[256];
    __shared__ unsigned sb3, srem3;
    if (tid == 0) { sb3 = 0; srem3 = 0; }
    s8[tid] = c8;
    __syncthreads();
    for (int off = 1; off < 256; off <<= 1) {
        unsigned vc = (tid + off < 256) ? s8[tid + off] : 0u;
        __syncthreads();
        s8[tid] += vc;
        __syncthreads();
    }
    unsigned above8 = (tid < 255) ? s8[tid + 1] : 0u;
    if (above8 < rem2 && above8 + c8 >= rem2) { sb3 = (unsigned)tid; srem3 = rem2 - above8; }
    __syncthreads();
    unsigned b3 = sb3, rem3 = srem3;
    // pass 3: sum of (sub == b2, low > b3)
    double s3 = 0.0;
    for (unsigned i = tid; i < n; i += 256) {
        float v = L[i];
        unsigned bits = __float_as_uint(v);
        if (((bits >> 8) & 0xFFFu) == b2 && (bits & 0xFFu) > b3) s3 += (double)v;
    }
    double tot = sMid + s3;
#pragma unroll
    for (int off = 32; off; off >>= 1) tot += __shfl_down(tot, off, 64);
    __shared__ double sred[4];
    int wv = tid >> 6, ln = tid & 63;
    if (ln == 0) sred[wv] = tot;
    __syncthreads();
    if (tid == 0) {
        double totAll = sred[0] + sred[1] + sred[2] + sred[3];
        unsigned vbits = (ch->b1 << 20) | (b2 << 8) | b3;
        ch->topk = ch->sumAbove + totAll + (double)rem3 * (double)__uint_as_float(vbits);
    }
}

// ---------- finalize ----------
__global__ void finalize_kernel(const Acc* __restrict__ acc,
                                const Chain* __restrict__ chains,
                                float* __restrict__ out)
{
    __shared__ double cl[BN], bl[BN];
    int t = threadIdx.x;
    if (t < BN) {
        unsigned np = acc[t].np, nn = acc[t].nn;
        double pos_sum = acc[t].pos_sum, bbox_sum = acc[t].bbox_sum;
        unsigned npc = max(np, 1u);
        double conf;
        if (nn > 0) {
            unsigned k = min(3u * np, nn);
            conf = (pos_sum + chains[t].topk) / (double)max(np + k, 1u);
        } else {
            conf = pos_sum / (double)npc;
        }
        cl[t] = conf;
        bl[t] = bbox_sum / (double)npc;
    }
    __syncthreads();
    if (t == 0) {
        double cs = 0, bs = 0;
        for (int i = 0; i < BN; ++i) { cs += cl[i]; bs += bl[i]; }
        cs /= BN; bs /= BN;
        out[0] = (float)(cs + bs);
        out[1] = (float)cs;
        out[2] = (float)bs;
    }
}

extern "C" void kernel_launch(void* const* d_in, const int* in_sizes, int n_in,
                              void* d_out, int out_size, void* d_ws, size_t ws_size,
                              hipStream_t stream)
{
    (void)in_sizes; (void)n_in; (void)out_size; (void)ws_size;
    const float*  conf    = (const float*)d_in[0];
    const float4* bboxp   = (const float4*)d_in[1];
    const float4* anchors = (const float4*)d_in[2];
    const float4* tboxes  = (const float4*)d_in[3];
    const int*    tlabels = (const int*)d_in[4];
    float* out = (float*)d_out;
    char* ws = (char*)d_ws;
    size_t off = 0;
    auto alloc = [&](size_t bytes) -> void* {
        void* p = (void*)(ws + off);
        off = (off + bytes + 255) & ~(size_t)255;
        return p;
    };
    unsigned* maxb     = (unsigned*)alloc((size_t)BN * AN * 4);
    int*      cand     = (int*)alloc((size_t)BN * AN * 4);
    float*    list     = (float*)alloc((size_t)BN * AN * 4);
    BlockAcc* blockAcc = (BlockAcc*)alloc((size_t)BN * 256 * sizeof(BlockAcc));
    Acc*      acc      = (Acc*)alloc(BN * sizeof(Acc));
    size_t zstart = off;
    unsigned long long* gbest = (unsigned long long*)alloc((size_t)BN * TN * 8);
    Chain*    chains   = (Chain*)alloc(BN * sizeof(Chain));
    unsigned* ahist    = (unsigned*)alloc((size_t)BN * NBA * 4);
    unsigned* cand_cnt = (unsigned*)alloc((size_t)BN * 4);
    unsigned* cnt1     = (unsigned*)alloc((size_t)BN * NBA * 4);
    unsigned* listCnt  = (unsigned*)alloc((size_t)BN * 4);
    size_t zbytes = off - zstart;
    hipMemsetAsync(ws + zstart, 0, zbytes, stream);

    dim3 gridA(AN / 256, BN);
    dim3 gridH(32, BN);
    main_kernel<<<gridA, 256, 0, stream>>>(conf, bboxp, anchors, tboxes, tlabels,
                                           gbest, ahist, maxb, blockAcc);
    force_sel0_kernel<<<BN, 256, 0, stream>>>(conf, bboxp, anchors, tboxes, tlabels,
                                              gbest, blockAcc, ahist, maxb, acc, chains);
    compact_kernel<<<gridA, 256, 0, stream>>>(maxb, chains, cand, cand_cnt);
    hist1_kernel<<<gridH, 256, 0, stream>>>(conf, cand, cand_cnt, chains, cnt1);
    refine2_kernel<<<gridH, 256, 0, stream>>>(conf, cand, cand_cnt, cnt1, chains, list, listCnt);
    selectF_kernel<<<BN, 256, 0, stream>>>(list, listCnt, chains);
    finalize_kernel<<<1, 64, 0, stream>>>(acc, chains, out);
}

// Round 8
// 271.220 us; speedup vs baseline: 1.3393x; 1.0640x over previous
//
#include <hip/hip_runtime.h>

// DetectionLoss: B=16, A=65536, T=32, C=21.
// R8: 3 graph nodes (memset, main, tail). main = R7 proven + aaS. tail = one
// block per image doing force-fix -> totals -> threshold -> compact -> hist ->
// select1 -> refine2 -> selectF -> per-image result; last block averages.

#define AN 65536
#define BN 16
#define TN 32
#define CN 21
#define NBA 2048   // anchor/cell L1 bins = focal bits >> 20

struct BlockAcc { float pos_sum; float bbox_sum; unsigned np; unsigned nn; };

// ---------- shared math: bit-identical across kernels (_rn-pinned, shared fns) ----------
__device__ __forceinline__ float box_area(float4 B) {
    return __fmul_rn(__fsub_rn(B.z, B.x), __fsub_rn(B.w, B.y));
}
__device__ __forceinline__ float iou_rcp(float4 A, float aa, float4 T, float ta) {
    float x1 = fmaxf(A.x, T.x), y1 = fmaxf(A.y, T.y);
    float x2 = fminf(A.z, T.z), y2 = fminf(A.w, T.w);
    float inter = __fmul_rn(fmaxf(__fsub_rn(x2, x1), 0.f), fmaxf(__fsub_rn(y2, y1), 0.f));
    float den = __fadd_rn(__fsub_rn(__fadd_rn(aa, ta), inter), 1e-6f);
    return __fmul_rn(inter, __builtin_amdgcn_rcpf(den));
}
__device__ __forceinline__ float row_prep(const float* __restrict__ row, float* __restrict__ c) {
#pragma unroll
    for (int j = 0; j < CN; ++j) c[j] = row[j];
    float m1[10];
#pragma unroll
    for (int j = 0; j < 10; ++j) m1[j] = fmaxf(c[j], c[j + 10]);
    float m2[5];
#pragma unroll
    for (int j = 0; j < 5; ++j) m2[j] = fmaxf(m1[j], m1[j + 5]);
    float ma = fmaxf(m2[0], m2[1]), mb = fmaxf(m2[2], m2[3]);
    float m = fmaxf(fmaxf(ma, mb), fmaxf(m2[4], c[20]));
#pragma unroll
    for (int j = 0; j < CN; ++j) c[j] = __expf(__fsub_rn(c[j], m));
    float s1[10];
#pragma unroll
    for (int j = 0; j < 10; ++j) s1[j] = __fadd_rn(c[j], c[j + 10]);
    float s2[5];
#pragma unroll
    for (int j = 0; j < 5; ++j) s2[j] = __fadd_rn(s1[j], s1[j + 5]);
    float sa = __fadd_rn(s2[0], s2[1]), sb = __fadd_rn(s2[2], s2[3]);
    float s = __fadd_rn(__fadd_rn(sa, sb), __fadd_rn(s2[4], c[20]));
    return __builtin_amdgcn_rcpf(s);
}
__device__ __forceinline__ float cell_focal(float cexp, float inv, bool cellpos) {
    float p = __fmul_rn(cexp, inv);
    float pt = cellpos ? p : __fsub_rn(1.0f, p);
    float af = cellpos ? 0.25f : 0.75f;
    float om = __fsub_rn(1.0f, pt);
    float lg = __logf(fmaxf(pt, 1e-6f));
    return __fmul_rn(__fmul_rn(__fmul_rn(-af, om), om), lg);
}
__device__ __forceinline__ unsigned focal_bits(float fo) {
    unsigned bits = __float_as_uint(fo);
    if (bits == 0x80000000u) bits = 0u;   // canonicalize -0.0
    return bits;
}
__device__ __forceinline__ float bbox_per(float4 b1, float4 b2) {
    float x1 = fmaxf(b1.x, b2.x), y1 = fmaxf(b1.y, b2.y);
    float x2 = fminf(b1.z, b2.z), y2 = fminf(b1.w, b2.w);
    float inter = fmaxf(x2 - x1, 0.f) * fmaxf(y2 - y1, 0.f);
    float a1 = (b1.z - b1.x) * (b1.w - b1.y);
    float a2 = (b2.z - b2.x) * (b2.w - b2.y);
    float un = a1 + a2 - inter;
    float iou = inter / (un + 1e-6f);
    float ex1 = fminf(b1.x, b2.x), ey1 = fminf(b1.y, b2.y);
    float ex2 = fmaxf(b1.z, b2.z), ey2 = fmaxf(b1.w, b2.w);
    float enc = (ex2 - ex1) * (ey2 - ey1);
    float giou = iou - (enc - un) / (enc + 1e-6f);
    float gl = 1.0f - giou;
    float l1 = 0.f, d, ad;
    d = b1.x - b2.x; ad = fabsf(d); l1 += (ad < 1.f) ? (0.5f * d * d) : (ad - 0.5f);
    d = b1.y - b2.y; ad = fabsf(d); l1 += (ad < 1.f) ? (0.5f * d * d) : (ad - 0.5f);
    d = b1.z - b2.z; ad = fabsf(d); l1 += (ad < 1.f) ? (0.5f * d * d) : (ad - 0.5f);
    d = b1.w - b2.w; ad = fabsf(d); l1 += (ad < 1.f) ? (0.5f * d * d) : (ad - 0.5f);
    return gl + 0.5f * (l1 * 0.25f);
}
__device__ __forceinline__ unsigned mbcnt64(unsigned long long m) {
    return __builtin_amdgcn_mbcnt_hi((unsigned)(m >> 32),
           __builtin_amdgcn_mbcnt_lo((unsigned)m, 0u));
}

// ---------- fused main: match + force-argmax + focal + anchor hist ----------
__global__ __launch_bounds__(256) void main_kernel(
    const float* __restrict__ conf, const float4* __restrict__ bboxp,
    const float4* __restrict__ anchors, const float4* __restrict__ tboxes,
    const int* __restrict__ tlabels,
    unsigned long long* __restrict__ gbest,
    unsigned* __restrict__ ahist, unsigned* __restrict__ maxb,
    BlockAcc* __restrict__ blockAcc)
{
    __shared__ float4 tbS[TN];
    __shared__ float4 aS[256];
    __shared__ float aaS[256];
    __shared__ int tlS[TN];
    __shared__ float taS[TN];
    __shared__ unsigned ahp[NBA / 2];      // packed 2 bins/u32
    __shared__ float pbV[TN][8];
    __shared__ int   pbA[TN][8];
    __shared__ float rF[2][4];
    __shared__ unsigned rI[2][4];
    int b = blockIdx.y, tid = threadIdx.x;
    int a = blockIdx.x * 256 + tid;
    for (int i = tid; i < NBA / 2; i += 256) ahp[i] = 0u;
    if (tid < TN) {
        float4 T = tboxes[b * TN + tid];
        tbS[tid] = T; tlS[tid] = tlabels[b * TN + tid]; taS[tid] = box_area(T);
    }
    float4 ab = anchors[a];
    aS[tid] = ab;
    float aa = box_area(ab);
    aaS[tid] = aa;
    __syncthreads();

    // phase 1: per-anchor max IoU over targets
    float best = -1.0f; int bt = 0;
#pragma unroll
    for (int t = 0; t < TN; ++t) {
        float iou = iou_rcp(ab, aa, tbS[t], taS[t]);
        if (iou > best) { best = iou; bt = t; }   // strict >: first-occurrence argmax
    }

    // phase 2: per-target best anchor within block (recompute from LDS, rcp)
    {
        int t = tid & 31, pp = tid >> 5;
        float4 T = tbS[t];
        float ta = taS[t];
        float bv = -1.f; int ba = 0;
#pragma unroll
        for (int i2 = 0; i2 < 32; ++i2) {
            int r = pp * 32 + i2;
            float iou = iou_rcp(aS[r], aaS[r], T, ta);
            if (iou > bv) { bv = iou; ba = r; }
        }
        pbV[t][pp] = bv; pbA[t][pp] = ba;
    }
    __syncthreads();
    if (tid < TN) {
        float bv = -1.f; int ba = 0;
#pragma unroll
        for (int pp = 0; pp < 8; ++pp) {
            float v = pbV[tid][pp];
            if (v > bv) { bv = v; ba = pbA[tid][pp]; }
        }
        unsigned ga = blockIdx.x * 256 + (unsigned)ba;
        unsigned long long key =
            (((unsigned long long)__float_as_uint(bv)) << 32) | (unsigned long long)(unsigned)(~ga);
        atomicMax(&gbest[b * TN + tid], key);   // tie -> smaller anchor idx
    }

    // phase 3: focal (threshold classification; forced anchors fixed in tail)
    size_t idx = (size_t)b * AN + a;
    bool posA = best >= 0.5f;
    bool negA = best < 0.4f;
    float fs = 0.f, bper = 0.f;
    unsigned mbenc = 0u;
    if (posA || negA) {
        int label = posA ? tlS[bt] : -1;
        float c[CN];
        float inv = row_prep(conf + idx * CN, c);
        unsigned mb = 0u;
#pragma unroll
        for (int j = 0; j < CN; ++j) {
            float fo = cell_focal(c[j], inv, j == label);
            fs += fo;
            mb = max(mb, focal_bits(fo));
        }
        if (negA) {
            mbenc = (mb << 1) | 1u;
            unsigned bin = mb >> 20;
            atomicAdd(&ahp[bin >> 1], 1u << ((bin & 1) << 4));
        } else {
            bper = bbox_per(bboxp[idx], tbS[bt]);
        }
    }
    maxb[idx] = mbenc;

    // block reduce {pos_sum, bbox_sum, np, nn} -> plain store
    float vpos = posA ? fs : 0.f, vb = bper;
    unsigned inp = posA ? 1u : 0u, inn = negA ? 1u : 0u;
#pragma unroll
    for (int off = 32; off; off >>= 1) {
        vpos += __shfl_down(vpos, off, 64);
        vb   += __shfl_down(vb,   off, 64);
        inp  += __shfl_down(inp,  off, 64);
        inn  += __shfl_down(inn,  off, 64);
    }
    int wv = tid >> 6, ln = tid & 63;
    if (ln == 0) { rF[0][wv] = vpos; rF[1][wv] = vb; rI[0][wv] = inp; rI[1][wv] = inn; }
    __syncthreads();
    if (tid == 0) {
        BlockAcc ba2;
        ba2.pos_sum = rF[0][0] + rF[0][1] + rF[0][2] + rF[0][3];
        ba2.bbox_sum = rF[1][0] + rF[1][1] + rF[1][2] + rF[1][3];
        ba2.np = rI[0][0] + rI[0][1] + rI[0][2] + rI[0][3];
        ba2.nn = rI[1][0] + rI[1][1] + rI[1][2] + rI[1][3];
        blockAcc[b * 256 + blockIdx.x] = ba2;
    }
    for (int i = tid; i < NBA / 2; i += 256) {
        unsigned v = ahp[i];
        if (v) {
            if (v & 0xFFFFu) atomicAdd(&ahist[b * NBA + 2 * i], v & 0xFFFFu);
            if (v >> 16)     atomicAdd(&ahist[b * NBA + 2 * i + 1], v >> 16);
        }
    }
}

// ---------- tail: everything after main, one block per image + last-block avg ----------
__global__ __launch_bounds__(1024) void tail_kernel(
    const float* __restrict__ conf, const float4* __restrict__ bboxp,
    const float4* __restrict__ anchors, const float4* __restrict__ tboxes,
    const int* __restrict__ tlabels,
    const unsigned long long* __restrict__ gbest,
    const BlockAcc* __restrict__ blockAcc,
    const unsigned* __restrict__ ahist, unsigned* __restrict__ maxb,
    int* __restrict__ cand, float* __restrict__ list,
    double* __restrict__ imgRes, unsigned* __restrict__ ctr,
    float* __restrict__ out)
{
    __shared__ unsigned hist[4096];     // reused: ahist copy / cell hist / h12 / h8
    __shared__ unsigned scan_[1024];
    __shared__ unsigned gaS[TN];
    __shared__ float4 tbS[TN];
    __shared__ int tlS[TN];
    __shared__ float taS[TN];
    __shared__ float dps[TN], dbb[TN];
    __shared__ int dnp[TN], dnn[TN];
    __shared__ double sdbl[16];
    __shared__ unsigned suns[16];
    __shared__ double s_pos, s_bbox, s_sumAbove, s_topk;
    __shared__ unsigned s_np, s_nn, s_k, s_act, s_ve, s_b1, s_rem, s_m, s_n, s_b2, s_rem2, s_b3, s_rem3;

    int b = blockIdx.x, tid = threadIdx.x;
    int wv = tid >> 6, ln = tid & 63;

    for (int i = tid; i < NBA; i += 1024) hist[i] = ahist[b * NBA + i];
    if (tid < TN) {
        gaS[tid] = ~(unsigned)(gbest[b * TN + tid] & 0xFFFFFFFFull);
        float4 T = tboxes[b * TN + tid];
        tbS[tid] = T; tlS[tid] = tlabels[b * TN + tid]; taS[tid] = box_area(T);
        dps[tid] = 0.f; dbb[tid] = 0.f; dnp[tid] = 0; dnn[tid] = 0;
    }
    if (tid == 0) { s_m = 0; s_n = 0; s_act = 0; s_sumAbove = 0.0; s_topk = 0.0;
                    s_b3 = 0; s_rem3 = 0; }
    __syncthreads();

    // ---- phase A: force-match fix (<=32 anchors) ----
    if (tid < TN) {
        bool doit = true;
        unsigned ga = gaS[tid];
        for (int u = 0; u < tid; ++u) if (gaS[u] == ga) doit = false;   // dedupe
        if (doit) {
            size_t idx = (size_t)b * AN + ga;
            float4 ab = anchors[ga];
            float aa = box_area(ab);
            float best = -1.f; int bt = 0;
#pragma unroll
            for (int t = 0; t < TN; ++t) {
                float iou = iou_rcp(ab, aa, tbS[t], taS[t]);   // bit-identical to main
                if (iou > best) { best = iou; bt = t; }
            }
            if (best < 0.5f) {
                int label = tlS[bt];
                float c[CN];
                float inv = row_prep(conf + idx * CN, c);
                float fsv = 0.f;
#pragma unroll
                for (int j = 0; j < CN; ++j) fsv += cell_focal(c[j], inv, j == label);
                dps[tid] = fsv;
                dbb[tid] = bbox_per(bboxp[idx], tbS[bt]);
                dnp[tid] = 1;
                if (best < 0.4f) {   // was counted neg: undo
                    unsigned enc = maxb[idx];
                    atomicSub(&hist[enc >> 21], 1u);
                    maxb[idx] = 0u;
                    dnn[tid] = -1;
                }
            }
        }
    }
    __syncthreads();

    // ---- phase B: totals ----
    if (tid < 256) {
        BlockAcc ba = blockAcc[b * 256 + tid];
        double ps = (double)ba.pos_sum, bs = (double)ba.bbox_sum;
        unsigned np = ba.np, nn = ba.nn;
#pragma unroll
        for (int off = 32; off; off >>= 1) {
            ps += __shfl_down(ps, off, 64);
            bs += __shfl_down(bs, off, 64);
            np += __shfl_down(np, off, 64);
            nn += __shfl_down(nn, off, 64);
        }
        if (ln == 0) { sdbl[wv] = ps; sdbl[8 + wv] = bs; suns[wv] = np; suns[8 + wv] = nn; }
    }
    __syncthreads();
    if (tid == 0) {
        double dp = 0, db = 0; int cp = 0, cn = 0;
        for (int i = 0; i < TN; ++i) { dp += dps[i]; db += dbb[i]; cp += dnp[i]; cn += dnn[i]; }
        s_pos = sdbl[0] + sdbl[1] + sdbl[2] + sdbl[3] + dp;
        s_bbox = sdbl[8] + sdbl[9] + sdbl[10] + sdbl[11] + db;
        unsigned NP = (unsigned)((int)(suns[0] + suns[1] + suns[2] + suns[3]) + cp);
        unsigned NN = (unsigned)((int)(suns[8] + suns[9] + suns[10] + suns[11]) + cn);
        s_np = NP; s_nn = NN;
        unsigned k = min(3u * NP, NN);
        s_k = k;
        s_act = (NN > 0 && k > 0) ? 1u : 0u;
    }
    __syncthreads();

    if (s_act) {
        unsigned k = s_k;
        // ---- phase C: anchor-max threshold (2048 bins, 2/thread, suffix scan) ----
        unsigned lc0 = hist[tid * 2], lc1 = hist[tid * 2 + 1];
        unsigned cc = lc0 + lc1;
        scan_[tid] = cc;
        __syncthreads();
        for (int off = 1; off < 1024; off <<= 1) {
            unsigned v = (tid + off < 1024) ? scan_[tid + off] : 0u;
            __syncthreads();
            scan_[tid] += v;
            __syncthreads();
        }
        {
            unsigned above = (tid < 1023) ? scan_[tid + 1] : 0u;
            if (above < k && above + cc >= k) {
                unsigned bin = (above + lc1 >= k) ? (unsigned)(tid * 2 + 1) : (unsigned)(tid * 2);
                s_ve = (bin << 21) | 1u;
            }
        }
        __syncthreads();
        unsigned ve = s_ve, vbits = ve >> 1;

        // ---- phase D: compact candidates (ballot, zero global atomics) ----
        const uint4* mb4 = (const uint4*)(maxb + (size_t)b * AN);
        for (int it = 0; it < 16; ++it) {
            uint4 m4 = mb4[it * 1024 + tid];
            int a0 = it * 4096 + tid * 4;
            bool q0 = m4.x >= ve, q1 = m4.y >= ve, q2 = m4.z >= ve, q3 = m4.w >= ve;
            unsigned long long k0 = __ballot(q0), k1 = __ballot(q1);
            unsigned long long k2 = __ballot(q2), k3 = __ballot(q3);
            unsigned p0 = (unsigned)__popcll(k0), p1 = (unsigned)__popcll(k1);
            unsigned p2 = (unsigned)__popcll(k2), p3 = (unsigned)__popcll(k3);
            if (ln == 0) scan_[wv] = p0 + p1 + p2 + p3;
            __syncthreads();
            if (tid == 0) {
                unsigned run = s_m;
                for (int w = 0; w < 16; ++w) { unsigned t2 = scan_[w]; scan_[w] = run; run += t2; }
                s_m = run;
            }
            __syncthreads();
            unsigned wb = scan_[wv];
            if (q0) cand[(size_t)b * AN + wb + mbcnt64(k0)] = a0 + 0;
            if (q1) cand[(size_t)b * AN + wb + p0 + mbcnt64(k1)] = a0 + 1;
            if (q2) cand[(size_t)b * AN + wb + p0 + p1 + mbcnt64(k2)] = a0 + 2;
            if (q3) cand[(size_t)b * AN + wb + p0 + p1 + p2 + mbcnt64(k3)] = a0 + 3;
            __syncthreads();
        }
        unsigned m = s_m;

        // ---- phase E: cell histogram over candidates ----
        for (int i = tid; i < NBA; i += 1024) hist[i] = 0u;
        __syncthreads();
        for (unsigned i = tid; i < m; i += 1024) {
            int a = cand[(size_t)b * AN + i];
            size_t idx = (size_t)b * AN + a;
            float c[CN];
            float inv = row_prep(conf + idx * CN, c);
#pragma unroll
            for (int j = 0; j < CN; ++j) {
                float fo = cell_focal(c[j], inv, false);
                unsigned bits = focal_bits(fo);
                if (bits >= vbits) atomicAdd(&hist[bits >> 20], 1u);
            }
        }
        __syncthreads();

        // ---- phase F: select1 ----
        lc0 = hist[tid * 2]; lc1 = hist[tid * 2 + 1]; cc = lc0 + lc1;
        scan_[tid] = cc;
        __syncthreads();
        for (int off = 1; off < 1024; off <<= 1) {
            unsigned v = (tid + off < 1024) ? scan_[tid + off] : 0u;
            __syncthreads();
            scan_[tid] += v;
            __syncthreads();
        }
        {
            unsigned total = scan_[0];
            unsigned above = (tid < 1023) ? scan_[tid + 1] : 0u;
            unsigned r = min(k, total);
            if (r > 0 && above < r && above + cc >= r) {
                if (above + lc1 >= r) { s_b1 = (unsigned)(tid * 2 + 1); s_rem = r - above; }
                else { s_b1 = (unsigned)(tid * 2); s_rem = r - above - lc1; }
            }
        }
        __syncthreads();
        unsigned b1 = s_b1, rem = s_rem;

        // ---- phase G: refine2 (sumAbove + wave-aggregated boundary list) ----
        double sA = 0.0;
        for (unsigned i = tid; i < m; i += 1024) {
            int a = cand[(size_t)b * AN + i];
            size_t idx = (size_t)b * AN + a;
            float c[CN];
            float inv = row_prep(conf + idx * CN, c);
#pragma unroll
            for (int j = 0; j < CN; ++j) {
                float fo = cell_focal(c[j], inv, false);
                unsigned bits = focal_bits(fo);
                unsigned hi = bits >> 20;
                if (hi > b1) sA += (double)fo;
                bool hit = (hi == b1);
                unsigned long long msk = __ballot(hit);
                if (hit) {
                    unsigned pre = mbcnt64(msk);
                    unsigned base = 0;
                    if (pre == 0) base = atomicAdd(&s_n, (unsigned)__popcll(msk));
                    base = __shfl(base, (int)(__ffsll((long long)msk) - 1), 64);
                    list[(size_t)b * AN + base + pre] = __uint_as_float(bits);  // canonicalized
                }
            }
        }
#pragma unroll
        for (int off = 32; off; off >>= 1) sA += __shfl_down(sA, off, 64);
        if (ln == 0) sdbl[wv] = sA;
        __syncthreads();
        if (tid == 0) {
            double tt = 0;
            for (int w = 0; w < 16; ++w) tt += sdbl[w];
            s_sumAbove = tt;
        }
        __syncthreads();
        unsigned n = s_n;
        double sumAbove = s_sumAbove;

        // ---- phase H: selectF (3 passes over list) ----
        if (rem == 0 || n == 0) {
            if (tid == 0) s_topk = sumAbove;
            __syncthreads();
        } else {
            for (int i = tid; i < 4096; i += 1024) hist[i] = 0u;
            __syncthreads();
            for (unsigned i = tid; i < n; i += 1024)
                atomicAdd(&hist[(__float_as_uint(list[(size_t)b * AN + i]) >> 8) & 0xFFFu], 1u);
            __syncthreads();
            unsigned l4[4], cc4 = 0;
#pragma unroll
            for (int q = 0; q < 4; ++q) { l4[q] = hist[tid * 4 + q]; cc4 += l4[q]; }
            scan_[tid] = cc4;
            __syncthreads();
            for (int off = 1; off < 1024; off <<= 1) {
                unsigned v = (tid + off < 1024) ? scan_[tid + off] : 0u;
                __syncthreads();
                scan_[tid] += v;
                __syncthreads();
            }
            {
                unsigned total = scan_[0];
                unsigned above = (tid < 1023) ? scan_[tid + 1] : 0u;
                unsigned r = min(rem, total);
                if (above < r && above + cc4 >= r) {
                    unsigned a2 = above;
                    for (int i = 3; i >= 0; --i) {
                        unsigned bc = l4[i];
                        if (a2 + bc >= r) { s_b2 = (unsigned)(tid * 4 + i); s_rem2 = r - a2; break; }
                        a2 += bc;
                    }
                }
            }
            __syncthreads();
            unsigned b2 = s_b2, rem2 = s_rem2;
            if (tid < 256) hist[tid] = 0u;
            __syncthreads();
            double sMid = 0.0;
            for (unsigned i = tid; i < n; i += 1024) {
                float v = list[(size_t)b * AN + i];
                unsigned bits = __float_as_uint(v);
                unsigned sub = (bits >> 8) & 0xFFFu;
                if (sub > b2) sMid += (double)v;
                else if (sub == b2) atomicAdd(&hist[bits & 0xFFu], 1u);
            }
            __syncthreads();
            if (tid < 256) scan_[tid] = hist[tid];
            __syncthreads();
            for (int off = 1; off < 256; off <<= 1) {
                unsigned v = 0;
                if (tid < 256 && tid + off < 256) v = scan_[tid + off];
                __syncthreads();
                if (tid < 256) scan_[tid] += v;
                __syncthreads();
            }
            if (tid < 256) {
                unsigned above8 = (tid < 255) ? scan_[tid + 1] : 0u;
                unsigned c8 = hist[tid];
                if (above8 < rem2 && above8 + c8 >= rem2) { s_b3 = (unsigned)tid; s_rem3 = rem2 - above8; }
            }
            __syncthreads();
            unsigned b3 = s_b3, rem3 = s_rem3;
            double s3 = 0.0;
            for (unsigned i = tid; i < n; i += 1024) {
                float v = list[(size_t)b * AN + i];
                unsigned bits = __float_as_uint(v);
                if (((bits >> 8) & 0xFFFu) == b2 && (bits & 0xFFu) > b3) s3 += (double)v;
            }
            double tot = sMid + s3;
#pragma unroll
            for (int off = 32; off; off >>= 1) tot += __shfl_down(tot, off, 64);
            if (ln == 0) sdbl[wv] = tot;
            __syncthreads();
            if (tid == 0) {
                double totAll = 0;
                for (int w = 0; w < 16; ++w) totAll += sdbl[w];
                unsigned vb3 = (b1 << 20) | (b2 << 8) | b3;
                s_topk = sumAbove + totAll + (double)rem3 * (double)__uint_as_float(vb3);
            }
            __syncthreads();
        }
    }

    // ---- per-image result + last-block average ----
    if (tid == 0) {
        unsigned np = s_np, nn = s_nn, k = s_k;
        double confl;
        if (s_act) confl = (s_pos + s_topk) / (double)max(np + k, 1u);
        else       confl = s_pos / (double)max(np, 1u);
        imgRes[b * 2 + 0] = confl;
        imgRes[b * 2 + 1] = s_bbox / (double)max(np, 1u);
        __threadfence();
        unsigned prev = atomicAdd(ctr, 1u);
        if (prev == BN - 1) {
            __threadfence();
            double cs = 0, bs = 0;
            for (int i = 0; i < BN; ++i) { cs += imgRes[i * 2]; bs += imgRes[i * 2 + 1]; }
            cs /= BN; bs /= BN;
            out[0] = (float)(cs + bs);
            out[1] = (float)cs;
            out[2] = (float)bs;
        }
    }
}

extern "C" void kernel_launch(void* const* d_in, const int* in_sizes, int n_in,
                              void* d_out, int out_size, void* d_ws, size_t ws_size,
                              hipStream_t stream)
{
    (void)in_sizes; (void)n_in; (void)out_size; (void)ws_size;
    const float*  conf    = (const float*)d_in[0];
    const float4* bboxp   = (const float4*)d_in[1];
    const float4* anchors = (const float4*)d_in[2];
    const float4* tboxes  = (const float4*)d_in[3];
    const int*    tlabels = (const int*)d_in[4];
    float* out = (float*)d_out;
    char* ws = (char*)d_ws;
    size_t off = 0;
    auto alloc = [&](size_t bytes) -> void* {
        void* p = (void*)(ws + off);
        off = (off + bytes + 255) & ~(size_t)255;
        return p;
    };
    unsigned* maxb     = (unsigned*)alloc((size_t)BN * AN * 4);
    int*      cand     = (int*)alloc((size_t)BN * AN * 4);
    float*    list     = (float*)alloc((size_t)BN * AN * 4);
    BlockAcc* blockAcc = (BlockAcc*)alloc((size_t)BN * 256 * sizeof(BlockAcc));
    double*   imgRes   = (double*)alloc((size_t)BN * 2 * 8);
    size_t zstart = off;
    unsigned long long* gbest = (unsigned long long*)alloc((size_t)BN * TN * 8);
    unsigned* ahist = (unsigned*)alloc((size_t)BN * NBA * 4);
    unsigned* ctr   = (unsigned*)alloc(256);
    size_t zbytes = off - zstart;
    hipMemsetAsync(ws + zstart, 0, zbytes, stream);

    dim3 gridA(AN / 256, BN);
    main_kernel<<<gridA, 256, 0, stream>>>(conf, bboxp, anchors, tboxes, tlabels,
                                           gbest, ahist, maxb, blockAcc);
    tail_kernel<<<BN, 1024, 0, stream>>>(conf, bboxp, anchors, tboxes, tlabels,
                                         gbest, blockAcc, ahist, maxb,
                                         cand, list, imgRes, ctr, out);
}